// Round 10
// baseline (404.172 us; speedup 1.0000x reference)
//
#include <hip/hip_runtime.h>
#include <cstdint>

// ---------------------------------------------------------------------------
// TransformerBlock MFMA v6.  B=2, S=2048, D=1024, FF=4096, H=16.
// External fp32; internal bf16; fp32 accumulate (MFMA 16x16x32).
// v6: GEMMs BK=128 as four BK=32 panels (64 MFMA per barrier pair, 2 blk/CU
// kept: 64/48 KB LDS); attn LDS stride 88->72 => 3 blocks/CU; Wp transpose
// folded into prep1; Vt relocated to d_out[8,16).
//
// FAST path (ws_size >= 40 MB):
//   d_out: hb[0,8) WTqkv[8,14) bcat@14MB -> Vt[8,16) -> fp32 residual [0,16)
//   ws: QKV[0,24), att[24,32), WTp[32,34)
//       -> h2[0,8), WT1[8,16), WT2[16,24), act[24,40)
// FALLBACK (ws < 40 MB): 24 MB scheme.
// ---------------------------------------------------------------------------

typedef __attribute__((ext_vector_type(8))) short short8;
typedef __attribute__((ext_vector_type(4))) float f32x4;

__device__ __forceinline__ float bf2f(unsigned short u) {
    union { unsigned int i; float f; } v; v.i = ((unsigned int)u) << 16; return v.f;
}
__device__ __forceinline__ unsigned short f2bf(float f) {
    union { float f; unsigned int i; } v; v.f = f;
    unsigned int u = v.i;
    u += 0x7fff + ((u >> 16) & 1);          // round-to-nearest-even
    return (unsigned short)(u >> 16);
}
__device__ __forceinline__ float gelu_f(float x) {
    float u = 0.7978845608028654f * (x + 0.044715f * x * x * x);
    float t = 1.f - 2.f / (__expf(2.f * u) + 1.f);   // tanh(u)
    return 0.5f * x * (1.f + t);
}
__device__ __forceinline__ void async16(const unsigned short* gp, unsigned short* lp) {
    __builtin_amdgcn_global_load_lds(
        (__attribute__((address_space(1))) void*)(gp),
        (__attribute__((address_space(3))) void*)(lp),
        16, 0, 0);
}

// ---------------------------------------------------------------------------
// device helpers for merged prep kernels (uniform per-block branch)
// ---------------------------------------------------------------------------
__device__ __forceinline__ void ln_dev(
    const float* __restrict__ x, const float* __restrict__ g,
    const float* __restrict__ b, unsigned short* __restrict__ o,
    int row, float* red)
{
    const int tid = threadIdx.x;
    const float4 v = ((const float4*)(x + (size_t)row * 1024))[tid];
    float f0 = v.x, f1 = v.y, f2 = v.z, f3 = v.w;
    float sum = f0 + f1 + f2 + f3;
    float sq  = f0 * f0 + f1 * f1 + f2 * f2 + f3 * f3;
    for (int off = 1; off < 64; off <<= 1) {
        sum += __shfl_xor(sum, off);
        sq  += __shfl_xor(sq,  off);
    }
    int wv = tid >> 6, ln = tid & 63;
    if (ln == 0) { red[wv] = sum; red[4 + wv] = sq; }
    __syncthreads();
    sum = red[0] + red[1] + red[2] + red[3];
    sq  = red[4] + red[5] + red[6] + red[7];
    float mu  = sum * (1.0f / 1024.0f);
    float var = sq  * (1.0f / 1024.0f) - mu * mu;
    float rsd = rsqrtf(fmaxf(var, 0.f) + 1e-5f);
    const float4 gg = ((const float4*)g)[tid];
    const float4 bb = ((const float4*)b)[tid];
    unsigned short* orow = o + (size_t)row * 1024;
    orow[4 * tid + 0] = f2bf((f0 - mu) * rsd * gg.x + bb.x);
    orow[4 * tid + 1] = f2bf((f1 - mu) * rsd * gg.y + bb.y);
    orow[4 * tid + 2] = f2bf((f2 - mu) * rsd * gg.z + bb.z);
    orow[4 * tid + 3] = f2bf((f3 - mu) * rsd * gg.w + bb.w);
}

__device__ __forceinline__ void transpose_dev(
    const float* __restrict__ in, unsigned short* __restrict__ out,
    int R, int C, int inStride, int bx, int by, unsigned short* tile /*64*70*/)
{
    const int tx = threadIdx.x & 15, ty = threadIdx.x >> 4;
    const int c0 = bx * 64, r0 = by * 64;
#pragma unroll
    for (int i = 0; i < 4; ++i) {
        int r = ty + 16 * i;
        float4 v = *(const float4*)(in + (size_t)(r0 + r) * inStride + c0 + tx * 4);
        tile[r * 70 + tx * 4 + 0] = f2bf(v.x);
        tile[r * 70 + tx * 4 + 1] = f2bf(v.y);
        tile[r * 70 + tx * 4 + 2] = f2bf(v.z);
        tile[r * 70 + tx * 4 + 3] = f2bf(v.w);
    }
    __syncthreads();
#pragma unroll
    for (int i = 0; i < 4; ++i) {
        int c = ty * 4 + i;
        ushort4 o;
        o.x = tile[(tx * 4 + 0) * 70 + c];
        o.y = tile[(tx * 4 + 1) * 70 + c];
        o.z = tile[(tx * 4 + 2) * 70 + c];
        o.w = tile[(tx * 4 + 3) * 70 + c];
        *(ushort4*)(out + (size_t)(c0 + c) * R + r0 + tx * 4) = o;
    }
}

// standalone versions (fallback path)
__global__ __launch_bounds__(256) void ln_k(
    const float* __restrict__ x, const float* __restrict__ g,
    const float* __restrict__ b, unsigned short* __restrict__ o)
{
    __shared__ float red[8];
    ln_dev(x, g, b, o, blockIdx.x, red);
}
__global__ __launch_bounds__(256) void transpose_f2b(
    const float* __restrict__ in, unsigned short* __restrict__ out,
    int R, int C, int inStride)
{
    __shared__ unsigned short tile[64 * 70];
    transpose_dev(in, out, R, C, inStride, blockIdx.x, blockIdx.y, tile);
}

// ---------------------------------------------------------------------------
// prep1: LN1 (4096) + Wq/Wk/Wv/Wp transposes (4x256) + bcat (12)
// ---------------------------------------------------------------------------
__global__ __launch_bounds__(256) void prep1_k(
    const float* __restrict__ x,
    const float* __restrict__ g1, const float* __restrict__ be1,
    const float* __restrict__ Wq, const float* __restrict__ Wk,
    const float* __restrict__ Wv, const float* __restrict__ Wp,
    const float* __restrict__ bq, const float* __restrict__ bk,
    const float* __restrict__ bv,
    unsigned short* __restrict__ hb,
    unsigned short* __restrict__ WTqkv,
    unsigned short* __restrict__ WTp,
    float* __restrict__ bcat)
{
    __shared__ unsigned short smem[64 * 70];
    const int b = blockIdx.x;
    if (b < 4096) {
        ln_dev(x, g1, be1, hb, b, (float*)smem);
    } else if (b < 4096 + 1024) {
        int t = b - 4096;
        int w = t >> 8;           // 0..3 -> Wq/Wk/Wv/Wp
        int tt = t & 255;
        const float* W = (w == 0) ? Wq : (w == 1) ? Wk : (w == 2) ? Wv : Wp;
        unsigned short* dst = (w < 3) ? WTqkv + (size_t)w * 1024 * 1024 : WTp;
        transpose_dev(W, dst, 1024, 1024, 1024, tt & 15, tt >> 4, smem);
    } else {
        int i = (b - 4096 - 1024) * 256 + threadIdx.x;
        float v = (i < 1024) ? bq[i] : (i < 2048) ? bk[i - 1024] : bv[i - 2048];
        bcat[i] = v;
    }
}

// ---------------------------------------------------------------------------
// prep2: LN2 (4096) + W1^T (1024 tiles) + W2^T (1024 tiles)
// ---------------------------------------------------------------------------
__global__ __launch_bounds__(256) void prep2_k(
    const float* __restrict__ x1,
    const float* __restrict__ g2, const float* __restrict__ be2,
    const float* __restrict__ W1, const float* __restrict__ W2,
    unsigned short* __restrict__ h2,
    unsigned short* __restrict__ WT1,
    unsigned short* __restrict__ WT2)
{
    __shared__ unsigned short smem[64 * 70];
    const int b = blockIdx.x;
    if (b < 4096) {
        ln_dev(x1, g2, be2, h2, b, (float*)smem);
    } else if (b < 4096 + 1024) {
        int t = b - 4096;                      // W1: R=1024 C=4096
        transpose_dev(W1, WT1, 1024, 4096, 4096, t & 63, t >> 6, smem);
    } else {
        int t = b - 4096 - 1024;               // W2: R=4096 C=1024
        transpose_dev(W2, WT2, 4096, 1024, 1024, t & 15, t >> 4, smem);
    }
}

// ---------------------------------------------------------------------------
// Per-head V transpose: src bf16 token-major [4096][stride] (V cols at
// (bh&15)*64), out Vt[bh][64][2048].  grid = (32 token-chunks, 32 bh).
// ---------------------------------------------------------------------------
__global__ __launch_bounds__(256) void vt_k(
    const unsigned short* __restrict__ src, int stride,
    unsigned short* __restrict__ Vt)
{
    __shared__ unsigned short tile[64][70];
    const int tx = threadIdx.x & 15, ty = threadIdx.x >> 4;
    const int t0 = blockIdx.x * 64;
    const int bh = blockIdx.y;
    const int bo = (bh >> 4) * 2048;
    const int ho = (bh & 15) * 64;
    const unsigned short* s = src + (size_t)bo * stride + ho;
#pragma unroll
    for (int i = 0; i < 4; ++i) {
        int r = ty + 16 * i;
        ushort4 v = *(const ushort4*)(s + (size_t)(t0 + r) * stride + tx * 4);
        tile[r][tx * 4 + 0] = v.x;
        tile[r][tx * 4 + 1] = v.y;
        tile[r][tx * 4 + 2] = v.z;
        tile[r][tx * 4 + 3] = v.w;
    }
    __syncthreads();
    unsigned short* dst = Vt + (size_t)bh * 64 * 2048;
#pragma unroll
    for (int i = 0; i < 4; ++i) {
        int d = ty * 4 + i;
        ushort4 o;
        o.x = tile[tx * 4 + 0][d];
        o.y = tile[tx * 4 + 1][d];
        o.z = tile[tx * 4 + 2][d];
        o.w = tile[tx * 4 + 3][d];
        *(ushort4*)(dst + (size_t)d * 2048 + t0 + tx * 4) = o;
    }
}

// ---------------------------------------------------------------------------
// C[M,N] = act( A[M,K] @ Bt[N,K]^T + bias ) (+ res)
// 128x128 tile, BK=128 as FOUR BK=32 panels: 64 MFMA per barrier pair.
// K must be a multiple of 128.  LDS 64 KB -> 2 blocks/CU.
// ---------------------------------------------------------------------------
__global__ __launch_bounds__(256, 2) void gemm_bt(
    const unsigned short* __restrict__ A,
    const unsigned short* __restrict__ Bt,
    const float* __restrict__ bias,
    const float* __restrict__ res,
    void* __restrict__ C,
    int M, int N, int K, int ldb, int dogelu, int out32)
{
    __shared__ unsigned short sA[4 * 128 * 32];   // panel p at p*4096
    __shared__ unsigned short sB[4 * 128 * 32];
    const int tid  = threadIdx.x;
    const int wave = tid >> 6;
    const int lane = tid & 63;
    const int quad = lane >> 4;
    const int l15  = lane & 15;
    const int bm = blockIdx.y * 128;
    const int bn = blockIdx.x * 128;
    const int wM = (wave >> 1) * 64;
    const int wN = (wave & 1) * 64;

    f32x4 acc[4][4];
#pragma unroll
    for (int i = 0; i < 4; ++i)
#pragma unroll
        for (int j = 0; j < 4; ++j)
            acc[i][j] = (f32x4){0.f, 0.f, 0.f, 0.f};

    const int rowS = tid >> 2;
    const int kcS  = (tid & 3) * 8;
    const unsigned short* gA  = A  + (size_t)(bm + rowS) * K + kcS;
    const unsigned short* gA2 = gA + (size_t)64 * K;
    const unsigned short* gB  = Bt + (size_t)(bn + rowS) * ldb + kcS;
    const unsigned short* gB2 = gB + (size_t)64 * ldb;
    unsigned short* lA  = sA + tid * 8;
    unsigned short* lA2 = lA + 64 * 32;
    unsigned short* lB  = sB + tid * 8;
    unsigned short* lB2 = lB + 64 * 32;

    for (int k0 = 0; k0 < K; k0 += 128) {
        __syncthreads();
#pragma unroll
        for (int p = 0; p < 4; ++p) {
            async16(gA + k0 + p * 32,  lA  + p * 4096);
            async16(gA2 + k0 + p * 32, lA2 + p * 4096);
            async16(gB + k0 + p * 32,  lB  + p * 4096);
            async16(gB2 + k0 + p * 32, lB2 + p * 4096);
        }
        __syncthreads();

#pragma unroll
        for (int p = 0; p < 4; ++p) {
            short8 aF[4], bF[4];
#pragma unroll
            for (int mi = 0; mi < 4; ++mi)
                aF[mi] = *(const short8*)(sA + p * 4096 + (wM + mi * 16 + l15) * 32 + quad * 8);
#pragma unroll
            for (int ni = 0; ni < 4; ++ni)
                bF[ni] = *(const short8*)(sB + p * 4096 + (wN + ni * 16 + l15) * 32 + quad * 8);
#pragma unroll
            for (int mi = 0; mi < 4; ++mi)
#pragma unroll
                for (int ni = 0; ni < 4; ++ni)
                    acc[mi][ni] = __builtin_amdgcn_mfma_f32_16x16x32_bf16(
                        aF[mi], bF[ni], acc[mi][ni], 0, 0, 0);
        }
    }

#pragma unroll
    for (int ni = 0; ni < 4; ++ni) {
        int col = bn + wN + ni * 16 + l15;
        float bv = bias ? bias[col] : 0.f;
#pragma unroll
        for (int mi = 0; mi < 4; ++mi) {
            int row = bm + wM + mi * 16 + quad * 4;
#pragma unroll
            for (int r = 0; r < 4; ++r) {
                float v = acc[mi][ni][r] + bv;
                if (dogelu) v = gelu_f(v);
                size_t idx = (size_t)(row + r) * N + col;
                if (res) v += res[idx];
                if (out32) ((float*)C)[idx] = v;
                else       ((unsigned short*)C)[idx] = f2bf(v);
            }
        }
    }
}

// ---------------------------------------------------------------------------
// 128x64-tile variant, BK=128 quad-panel.  LDS 48 KB.
// ---------------------------------------------------------------------------
__global__ __launch_bounds__(256, 2) void gemm_bt64(
    const unsigned short* __restrict__ A,
    const unsigned short* __restrict__ Bt,
    const float* __restrict__ bias,
    const float* __restrict__ res,
    void* __restrict__ C,
    int M, int N, int K, int ldb, int dogelu, int out32)
{
    __shared__ unsigned short sA[4 * 128 * 32];
    __shared__ unsigned short sB[4 * 64 * 32];
    const int tid  = threadIdx.x;
    const int wave = tid >> 6;
    const int lane = tid & 63;
    const int quad = lane >> 4;
    const int l15  = lane & 15;
    const int bm = blockIdx.y * 128;
    const int bn = blockIdx.x * 64;
    const int wM = wave * 32;

    f32x4 acc[2][4];
#pragma unroll
    for (int i = 0; i < 2; ++i)
#pragma unroll
        for (int j = 0; j < 4; ++j)
            acc[i][j] = (f32x4){0.f, 0.f, 0.f, 0.f};

    const int rowS = tid >> 2;
    const int kcS  = (tid & 3) * 8;
    const unsigned short* gA  = A  + (size_t)(bm + rowS) * K + kcS;
    const unsigned short* gA2 = gA + (size_t)64 * K;
    const unsigned short* gB  = Bt + (size_t)(bn + rowS) * ldb + kcS;
    unsigned short* lA  = sA + tid * 8;
    unsigned short* lA2 = lA + 64 * 32;
    unsigned short* lB  = sB + tid * 8;   // rows 0..63 only

    for (int k0 = 0; k0 < K; k0 += 128) {
        __syncthreads();
#pragma unroll
        for (int p = 0; p < 4; ++p) {
            async16(gA + k0 + p * 32,  lA  + p * 4096);
            async16(gA2 + k0 + p * 32, lA2 + p * 4096);
            async16(gB + k0 + p * 32,  lB  + p * 2048);
        }
        __syncthreads();

#pragma unroll
        for (int p = 0; p < 4; ++p) {
            short8 aF[2], bF[4];
#pragma unroll
            for (int mi = 0; mi < 2; ++mi)
                aF[mi] = *(const short8*)(sA + p * 4096 + (wM + mi * 16 + l15) * 32 + quad * 8);
#pragma unroll
            for (int ni = 0; ni < 4; ++ni)
                bF[ni] = *(const short8*)(sB + p * 2048 + (ni * 16 + l15) * 32 + quad * 8);
#pragma unroll
            for (int mi = 0; mi < 2; ++mi)
#pragma unroll
                for (int ni = 0; ni < 4; ++ni)
                    acc[mi][ni] = __builtin_amdgcn_mfma_f32_16x16x32_bf16(
                        aF[mi], bF[ni], acc[mi][ni], 0, 0, 0);
        }
    }

#pragma unroll
    for (int ni = 0; ni < 4; ++ni) {
        int col = bn + ni * 16 + l15;
        float bv = bias ? bias[col] : 0.f;
#pragma unroll
        for (int mi = 0; mi < 2; ++mi) {
            int row = bm + wM + mi * 16 + quad * 4;
#pragma unroll
            for (int r = 0; r < 4; ++r) {
                float v = acc[mi][ni][r] + bv;
                if (dogelu) v = gelu_f(v);
                size_t idx = (size_t)(row + r) * N + col;
                if (res) v += res[idx];
                if (out32) ((float*)C)[idx] = v;
                else       ((unsigned short*)C)[idx] = f2bf(v);
            }
        }
    }
}

// ---------------------------------------------------------------------------
// Flash attention, no-max softmax, MFMA ones-trick row sum.
// LDS stride 72 (144 B rows, 16B-aligned) -> 46 KB -> 3 blocks/CU.
// ---------------------------------------------------------------------------
__global__ __launch_bounds__(256, 3) void attn_k(
    const unsigned short* __restrict__ Q,
    const unsigned short* __restrict__ K,
    const unsigned short* __restrict__ Vt,
    unsigned short* __restrict__ O, int qs)
{
    __shared__ unsigned short sQ [128 * 72];
    __shared__ unsigned short sKP[128 * 72];
    __shared__ unsigned short sVt[64 * 72];

    const int tid  = threadIdx.x;
    const int wave = tid >> 6;
    const int lane = tid & 63;
    const int quad = lane >> 4;
    const int l15  = lane & 15;
    const int qb = blockIdx.x * 128;
    const int bh = blockIdx.y;
    const int bo = (bh >> 4) * 2048;
    const int ho = (bh & 15) * 64;

    const unsigned short* Qb  = Q  + (size_t)bo * qs + ho;
    const unsigned short* Kb  = K  + (size_t)bo * qs + ho;
    const unsigned short* Vtb = Vt + (size_t)bh * 64 * 2048;

    const int rowS = tid >> 3;
    const int dcS  = (tid & 7) * 8;

#pragma unroll
    for (int r = 0; r < 4; ++r) {
        int row = r * 32 + rowS;
        short8 v = *(const short8*)(Qb + (size_t)(qb + row) * qs + dcS);
        *(short8*)(sQ + row * 72 + dcS) = v;
    }

    short8 onesF;
#pragma unroll
    for (int j = 0; j < 8; ++j) onesF[j] = (short)0x3F80;

    f32x4 accO[2][4];
    f32x4 accL[2];
#pragma unroll
    for (int mi = 0; mi < 2; ++mi) {
        accL[mi] = (f32x4){0.f, 0.f, 0.f, 0.f};
#pragma unroll
        for (int nd = 0; nd < 4; ++nd) accO[mi][nd] = (f32x4){0.f, 0.f, 0.f, 0.f};
    }

    for (int kt = 0; kt < 2048; kt += 64) {
        __syncthreads();
#pragma unroll
        for (int r = 0; r < 2; ++r) {
            int row = r * 32 + rowS;
            short8 kv = *(const short8*)(Kb + (size_t)(kt + row) * qs + dcS);
            *(short8*)(sKP + row * 72 + dcS) = kv;
            short8 vv = *(const short8*)(Vtb + (size_t)row * 2048 + kt + dcS);
            *(short8*)(sVt + row * 72 + dcS) = vv;
        }
        __syncthreads();

        f32x4 accS[2][4];
#pragma unroll
        for (int mi = 0; mi < 2; ++mi)
#pragma unroll
            for (int ni = 0; ni < 4; ++ni) accS[mi][ni] = (f32x4){0.f, 0.f, 0.f, 0.f};
#pragma unroll
        for (int ks = 0; ks < 2; ++ks) {
            short8 aQ[2], bK[4];
#pragma unroll
            for (int mi = 0; mi < 2; ++mi)
                aQ[mi] = *(const short8*)(sQ + (wave * 32 + mi * 16 + l15) * 72 + ks * 32 + quad * 8);
#pragma unroll
            for (int ni = 0; ni < 4; ++ni)
                bK[ni] = *(const short8*)(sKP + (ni * 16 + l15) * 72 + ks * 32 + quad * 8);
#pragma unroll
            for (int mi = 0; mi < 2; ++mi)
#pragma unroll
                for (int ni = 0; ni < 4; ++ni)
                    accS[mi][ni] = __builtin_amdgcn_mfma_f32_16x16x32_bf16(
                        aQ[mi], bK[ni], accS[mi][ni], 0, 0, 0);
        }
        __syncthreads();

#pragma unroll
        for (int mi = 0; mi < 2; ++mi) {
            int prow = wave * 32 + mi * 16 + quad * 4;
#pragma unroll
            for (int r = 0; r < 4; ++r) {
                float p0 = __expf(accS[mi][0][r] * 0.125f);
                float p1 = __expf(accS[mi][1][r] * 0.125f);
                float p2 = __expf(accS[mi][2][r] * 0.125f);
                float p3 = __expf(accS[mi][3][r] * 0.125f);
                sKP[(prow + r) * 72 +      l15] = f2bf(p0);
                sKP[(prow + r) * 72 + 16 + l15] = f2bf(p1);
                sKP[(prow + r) * 72 + 32 + l15] = f2bf(p2);
                sKP[(prow + r) * 72 + 48 + l15] = f2bf(p3);
            }
        }

#pragma unroll
        for (int ks = 0; ks < 2; ++ks) {
            short8 aP[2], bV[4];
#pragma unroll
            for (int mi = 0; mi < 2; ++mi)
                aP[mi] = *(const short8*)(sKP + (wave * 32 + mi * 16 + l15) * 72 + ks * 32 + quad * 8);
#pragma unroll
            for (int nd = 0; nd < 4; ++nd)
                bV[nd] = *(const short8*)(sVt + (nd * 16 + l15) * 72 + ks * 32 + quad * 8);
#pragma unroll
            for (int mi = 0; mi < 2; ++mi) {
#pragma unroll
                for (int nd = 0; nd < 4; ++nd)
                    accO[mi][nd] = __builtin_amdgcn_mfma_f32_16x16x32_bf16(
                        aP[mi], bV[nd], accO[mi][nd], 0, 0, 0);
                accL[mi] = __builtin_amdgcn_mfma_f32_16x16x32_bf16(
                    aP[mi], onesF, accL[mi], 0, 0, 0);
            }
        }
    }

#pragma unroll
    for (int mi = 0; mi < 2; ++mi)
#pragma unroll
        for (int r = 0; r < 4; ++r) {
            int row = qb + wave * 32 + mi * 16 + quad * 4 + r;
            float inv = 1.f / accL[mi][r];
#pragma unroll
            for (int nd = 0; nd < 4; ++nd)
                O[(size_t)(bo + row) * 1024 + ho + nd * 16 + l15] =
                    f2bf(accO[mi][nd][r] * inv);
        }
}

// ---------------------------------------------------------------------------
extern "C" void kernel_launch(void* const* d_in, const int* in_sizes, int n_in,
                              void* d_out, int out_size, void* d_ws, size_t ws_size,
                              hipStream_t stream)
{
    (void)in_sizes; (void)n_in; (void)out_size;
    const float* x   = (const float*)d_in[0];
    const float* Wq  = (const float*)d_in[1];
    const float* bq  = (const float*)d_in[2];
    const float* Wk  = (const float*)d_in[3];
    const float* bk  = (const float*)d_in[4];
    const float* Wv  = (const float*)d_in[5];
    const float* bv  = (const float*)d_in[6];
    const float* Wp  = (const float*)d_in[7];
    const float* bp  = (const float*)d_in[8];
    const float* W1  = (const float*)d_in[9];
    const float* b1  = (const float*)d_in[10];
    const float* W2  = (const float*)d_in[11];
    const float* b2  = (const float*)d_in[12];
    const float* g1  = (const float*)d_in[13];
    const float* be1 = (const float*)d_in[14];
    const float* g2  = (const float*)d_in[15];
    const float* be2 = (const float*)d_in[16];
    float* out = (float*)d_out;

    char* ws = (char*)d_ws;
    char* dob = (char*)d_out;
    const size_t MB = 1024 * 1024;

    if (ws_size >= 40 * MB) {
        // ------------------------- FAST path -------------------------
        unsigned short* hb    = (unsigned short*)dob;             // [0,8)
        unsigned short* WTqkv = (unsigned short*)(dob + 8 * MB);  // [8,14)
        float*          bcat  = (float*)(dob + 14 * MB);
        unsigned short* Vt    = (unsigned short*)(dob + 8 * MB);  // [8,16) after QKV
        unsigned short* QKV   = (unsigned short*)ws;              // [0,24)
        unsigned short* att   = (unsigned short*)(ws + 24 * MB);  // [24,32)
        unsigned short* WTp   = (unsigned short*)(ws + 32 * MB);  // [32,34)
        unsigned short* h2    = (unsigned short*)ws;              // [0,8)
        unsigned short* WT1   = (unsigned short*)(ws + 8 * MB);   // [8,16)
        unsigned short* WT2   = (unsigned short*)(ws + 16 * MB);  // [16,24)
        unsigned short* act   = (unsigned short*)(ws + 24 * MB);  // [24,40)

        // LN1 + Wq/Wk/Wv/Wp transposes + bias concat
        prep1_k<<<4096 + 1024 + 12, 256, 0, stream>>>(
            x, g1, be1, Wq, Wk, Wv, Wp, bq, bk, bv, hb, WTqkv, WTp, bcat);
        // QKV = h @ [Wq|Wk|Wv] + bcat   [4096 x 3072]
        gemm_bt<<<dim3(24, 32), 256, 0, stream>>>(hb, WTqkv, bcat, nullptr, QKV,
                                                  4096, 3072, 1024, 1024, 0, 0);
        vt_k<<<dim3(32, 32), 256, 0, stream>>>(QKV + 2048, 3072, Vt);
        attn_k<<<dim3(16, 32), 256, 0, stream>>>(QKV, QKV + 1024, Vt, att, 3072);
        // x1 = x + att @ Wp + bp  -> d_out fp32
        gemm_bt64<<<dim3(16, 32), 256, 0, stream>>>(att, WTp, bp, x, out,
                                                    4096, 1024, 1024, 1024, 0, 1);
        // LN2 + W1/W2 transposes
        prep2_k<<<4096 + 2048, 256, 0, stream>>>(out, g2, be2, W1, W2, h2, WT1, WT2);
        for (int c = 0; c < 2; ++c) {
            gemm_bt<<<dim3(16, 32), 256, 0, stream>>>(h2, WT1 + (size_t)c * 2048 * 1024,
                                                      b1 + c * 2048, nullptr, act,
                                                      4096, 2048, 1024, 1024, 1, 0);
            gemm_bt64<<<dim3(16, 32), 256, 0, stream>>>(act, WT2 + (size_t)c * 2048,
                                                        c == 0 ? b2 : nullptr, out, out,
                                                        4096, 1024, 2048, 4096, 0, 1);
        }
    } else {
        // ---------------------- FALLBACK (24 MB) ----------------------
        unsigned short* Qw  = (unsigned short*)(ws);
        unsigned short* Kw  = (unsigned short*)(ws + 8 * MB);
        unsigned short* Vw  = (unsigned short*)(ws + 16 * MB);
        unsigned short* hb  = (unsigned short*)dob;
        unsigned short* WTq = (unsigned short*)(dob + 8 * MB);
        unsigned short* VtF = (unsigned short*)(dob + 8 * MB);
        unsigned short* att = Qw;
        unsigned short* WTb = Kw;
        unsigned short* h2  = Vw;
        unsigned short* act = Qw;

        ln_k<<<4096, 256, 0, stream>>>(x, g1, be1, hb);
        transpose_f2b<<<dim3(16, 16), 256, 0, stream>>>(Wq, WTq, 1024, 1024, 1024);
        gemm_bt<<<dim3(8, 32), 256, 0, stream>>>(hb, WTq, bq, nullptr, Qw, 4096, 1024, 1024, 1024, 0, 0);
        transpose_f2b<<<dim3(16, 16), 256, 0, stream>>>(Wk, WTq, 1024, 1024, 1024);
        gemm_bt<<<dim3(8, 32), 256, 0, stream>>>(hb, WTq, bk, nullptr, Kw, 4096, 1024, 1024, 1024, 0, 0);
        transpose_f2b<<<dim3(16, 16), 256, 0, stream>>>(Wv, WTq, 1024, 1024, 1024);
        gemm_bt<<<dim3(8, 32), 256, 0, stream>>>(hb, WTq, bv, nullptr, Vw, 4096, 1024, 1024, 1024, 0, 0);
        vt_k<<<dim3(32, 32), 256, 0, stream>>>(Vw, 1024, VtF);
        attn_k<<<dim3(16, 32), 256, 0, stream>>>(Qw, Kw, VtF, att, 1024);
        transpose_f2b<<<dim3(16, 16), 256, 0, stream>>>(Wp, WTb, 1024, 1024, 1024);
        gemm_bt64<<<dim3(16, 32), 256, 0, stream>>>(att, WTb, bp, x, out, 4096, 1024, 1024, 1024, 0, 1);
        ln_k<<<4096, 256, 0, stream>>>(out, g2, be2, h2);
        for (int c = 0; c < 4; ++c) {
            transpose_f2b<<<dim3(16, 16), 256, 0, stream>>>(W1 + c * 1024, WTb, 1024, 1024, 4096);
            gemm_bt64<<<dim3(16, 32), 256, 0, stream>>>(h2, WTb, b1 + c * 1024, nullptr, act,
                                                        4096, 1024, 1024, 1024, 1, 0);
            unsigned short* WT2c = WTb + 1024 * 1024;
            transpose_f2b<<<dim3(16, 16), 256, 0, stream>>>(W2 + (size_t)c * 1024 * 1024, WT2c,
                                                            1024, 1024, 1024);
            gemm_bt64<<<dim3(16, 32), 256, 0, stream>>>(act, WT2c, c == 0 ? b2 : nullptr,
                                                        out, out, 4096, 1024, 1024, 1024, 0, 1);
        }
    }
}